// Round 4
// baseline (119.267 us; speedup 1.0000x reference)
//
#include <hip/hip_runtime.h>

#define NUM_CP 64
#define D_MODEL 128

typedef float f32x4 __attribute__((ext_vector_type(4)));

// Exact algebraic collapse of the reference for t in [0,1]:
//   out[n][d] = B[d] + clip(t[n],0,1) * C[d]
//   B[d] = sum_{i=0}^{62} (1 - i) * cp[i][d]
//   C[d] = -cp[0][d] + sum_{i=1}^{62} cp[i][d]
//
// Single fused kernel: each thread reduces its own 4-dim coefficient slice
// (cp is 32 KB -> L1/L2 resident; one-time prologue), then streams output.
// Wave layout per iteration: lanes 0-31 -> rows R0..R0+3 (lane = float4
// column c), lanes 32-63 -> rows R0+4..R0+7. One f32x4 t-load (broadcast
// within half-wave), 16 FMAs, 4 plain float4 stores (each store = two
// contiguous 512 B segments; full-line coverage -> L2 write-combines).
__global__ __launch_bounds__(256) void spline_fused(const float* __restrict__ t,
                                                    const float* __restrict__ cp,
                                                    float* __restrict__ out, int n) {
    const int lane = threadIdx.x & 63;
    const int c    = lane & 31;        // float4 column (0..31) -> dims 4c..4c+3
    const int half = lane >> 5;        // 0 or 1

    // ---- coefficient reduction (double accum, one-time) ----
    const f32x4* __restrict__ cpq = reinterpret_cast<const f32x4*>(cp);
    f32x4 v0 = cpq[c];                 // cp[0], dims 4c..4c+3
    double B[4], C[4];
#pragma unroll
    for (int k = 0; k < 4; ++k) { B[k] = (double)v0[k]; C[k] = -(double)v0[k]; }
    for (int i = 1; i < NUM_CP - 1; ++i) {
        f32x4 v = cpq[i * 32 + c];
        const double w = 1.0 - (double)i;
#pragma unroll
        for (int k = 0; k < 4; ++k) {
            B[k] += w * (double)v[k];
            C[k] += (double)v[k];
        }
    }
    f32x4 b, cv;
#pragma unroll
    for (int k = 0; k < 4; ++k) { b[k] = (float)B[k]; cv[k] = (float)C[k]; }

    // ---- streaming evaluation ----
    const int waveGlobal = blockIdx.x * 4 + (threadIdx.x >> 6);
    const int nWaves     = gridDim.x * 4;
    const int rowStride  = nWaves * 8;
    f32x4* __restrict__ outq = reinterpret_cast<f32x4*>(out);

    for (int R0 = waveGlobal * 8; R0 < n; R0 += rowStride) {
        const int R = R0 + half * 4;   // this thread's 4 rows: R..R+3
        if (R + 3 < n) {
            f32x4 t4 = *reinterpret_cast<const f32x4*>(t + R);
            float tv[4];
#pragma unroll
            for (int k = 0; k < 4; ++k) tv[k] = fminf(fmaxf(t4[k], 0.0f), 1.0f);
#pragma unroll
            for (int k = 0; k < 4; ++k) {
                f32x4 o;
                o.x = fmaf(tv[k], cv.x, b.x);
                o.y = fmaf(tv[k], cv.y, b.y);
                o.z = fmaf(tv[k], cv.z, b.z);
                o.w = fmaf(tv[k], cv.w, b.w);
                outq[(R + k) * 32 + c] = o;
            }
        } else {
            for (int k = 0; k < 4; ++k) {
                const int r = R + k;
                if (r < n) {
                    float tv = fminf(fmaxf(t[r], 0.0f), 1.0f);
                    f32x4 o;
                    o.x = fmaf(tv, cv.x, b.x);
                    o.y = fmaf(tv, cv.y, b.y);
                    o.z = fmaf(tv, cv.z, b.z);
                    o.w = fmaf(tv, cv.w, b.w);
                    outq[r * 32 + c] = o;
                }
            }
        }
    }
}

extern "C" void kernel_launch(void* const* d_in, const int* in_sizes, int n_in,
                              void* d_out, int out_size, void* d_ws, size_t ws_size,
                              hipStream_t stream) {
    const float* t  = (const float*)d_in[0];
    const float* cp = (const float*)d_in[1];
    float* out = (float*)d_out;
    const int n = in_sizes[0];

    // 2048 blocks x 256 threads = 8 blocks/CU -> full 32-wave occupancy.
    const int waveTasks  = (n + 7) / 8;          // 8 rows per wave-iter
    const int wantBlocks = (waveTasks + 3) / 4;  // 4 waves per block
    const int blocks = wantBlocks < 2048 ? wantBlocks : 2048;
    spline_fused<<<blocks, 256, 0, stream>>>(t, cp, out, n);
}

// Round 5
// 116.090 us; speedup vs baseline: 1.0274x; 1.0274x over previous
//
#include <hip/hip_runtime.h>

#define NUM_CP 64
#define D_MODEL 128

typedef float f32x4 __attribute__((ext_vector_type(4)));

// Exact algebraic collapse of the reference for t in [0,1]:
//   out[n][d] = B[d] + clip(t[n],0,1) * C[d]
//   B[d] = sum_{i=0}^{62} (1 - i) * cp[i][d]
//   C[d] = -cp[0][d] + sum_{i=1}^{62} cp[i][d]
//
// Single fused kernel. Coefficients are reduced ONCE PER BLOCK (f32, into
// LDS) instead of per-thread (R4's mistake: 520 MB of redundant L1 traffic
// + FP64 ≈ 13 us). Per-block cost: 128 threads x 63 scalar L1-warm loads
// ≈ 1-2 us total across the grid.
__global__ __launch_bounds__(256) void spline_fused(const float* __restrict__ t,
                                                    const float* __restrict__ cp,
                                                    float* __restrict__ out, int n) {
    __shared__ float sbc[2 * D_MODEL];

    const int tid = threadIdx.x;
    if (tid < D_MODEL) {
        const int d = tid;
        float v0 = cp[d];              // cp[0][d]
        float B = v0, C = -v0;
        for (int i = 1; i < NUM_CP - 1; ++i) {
            float v = cp[i * D_MODEL + d];
            B = fmaf(1.0f - (float)i, v, B);
            C += v;
        }
        sbc[d] = B;
        sbc[D_MODEL + d] = C;
    }
    __syncthreads();

    const int lane = tid & 63;
    const int c    = lane & 31;        // float4 column (0..31) -> dims 4c..4c+3
    const int half = lane >> 5;        // 0 or 1

    const f32x4 b  = reinterpret_cast<const f32x4*>(sbc)[c];
    const f32x4 cv = reinterpret_cast<const f32x4*>(sbc + D_MODEL)[c];

    // Wave layout per iteration: lanes 0-31 -> rows R0..R0+3 (lane = float4
    // column c), lanes 32-63 -> rows R0+4..R0+7. One f32x4 t-load per thread
    // (covers its 4 rows), 16 FMAs, 4 float4 stores (each store instruction
    // = two contiguous 512 B segments).
    const int waveGlobal = blockIdx.x * 4 + (tid >> 6);
    const int nWaves     = gridDim.x * 4;
    const int rowStride  = nWaves * 8;
    f32x4* __restrict__ outq = reinterpret_cast<f32x4*>(out);

    for (int R0 = waveGlobal * 8; R0 < n; R0 += rowStride) {
        const int R = R0 + half * 4;   // this thread's 4 rows: R..R+3
        if (R + 3 < n) {
            f32x4 t4 = *reinterpret_cast<const f32x4*>(t + R);
            float tv[4];
#pragma unroll
            for (int k = 0; k < 4; ++k) tv[k] = fminf(fmaxf(t4[k], 0.0f), 1.0f);
#pragma unroll
            for (int k = 0; k < 4; ++k) {
                f32x4 o;
                o.x = fmaf(tv[k], cv.x, b.x);
                o.y = fmaf(tv[k], cv.y, b.y);
                o.z = fmaf(tv[k], cv.z, b.z);
                o.w = fmaf(tv[k], cv.w, b.w);
                outq[(R + k) * 32 + c] = o;
            }
        } else {
            for (int k = 0; k < 4; ++k) {
                const int r = R + k;
                if (r < n) {
                    float tv = fminf(fmaxf(t[r], 0.0f), 1.0f);
                    f32x4 o;
                    o.x = fmaf(tv, cv.x, b.x);
                    o.y = fmaf(tv, cv.y, b.y);
                    o.z = fmaf(tv, cv.z, b.z);
                    o.w = fmaf(tv, cv.w, b.w);
                    outq[r * 32 + c] = o;
                }
            }
        }
    }
}

extern "C" void kernel_launch(void* const* d_in, const int* in_sizes, int n_in,
                              void* d_out, int out_size, void* d_ws, size_t ws_size,
                              hipStream_t stream) {
    const float* t  = (const float*)d_in[0];
    const float* cp = (const float*)d_in[1];
    float* out = (float*)d_out;
    const int n = in_sizes[0];

    // 2048 blocks x 256 threads = 8 blocks/CU -> full 32-wave occupancy.
    const int waveTasks  = (n + 7) / 8;          // 8 rows per wave-iter
    const int wantBlocks = (waveTasks + 3) / 4;  // 4 waves per block
    const int blocks = wantBlocks < 2048 ? wantBlocks : 2048;
    spline_fused<<<blocks, 256, 0, stream>>>(t, cp, out, n);
}

// Round 6
// 103.525 us; speedup vs baseline: 1.1521x; 1.1214x over previous
//
#include <hip/hip_runtime.h>

#define NUM_CP 64
#define D_MODEL 128

typedef float f32x4 __attribute__((ext_vector_type(4)));

// Exact algebraic collapse of the reference for t in [0,1]:
//   out[n][d] = B[d] + clip(t[n],0,1) * C[d]
//   B[d] = sum_{i=0}^{62} (1 - i) * cp[i][d]
//   C[d] = -cp[0][d] + sum_{i=1}^{62} cp[i][d]
//
// Single fused kernel. Coefficients reduced once per block (f32, into LDS;
// ~1-2 us grid-wide). Streaming loop uses NONTEMPORAL stores: R3 vs R5 A/B
// isolated NT ≈ +10-14 us over plain (512 MB write stream is never re-read;
// plain stores dirty L2 and force writeback contention with t reads).
__global__ __launch_bounds__(256) void spline_fused(const float* __restrict__ t,
                                                    const float* __restrict__ cp,
                                                    float* __restrict__ out, int n) {
    __shared__ float sbc[2 * D_MODEL];

    const int tid = threadIdx.x;
    if (tid < D_MODEL) {
        const int d = tid;
        float v0 = cp[d];              // cp[0][d]
        float B = v0, C = -v0;
        for (int i = 1; i < NUM_CP - 1; ++i) {
            float v = cp[i * D_MODEL + d];
            B = fmaf(1.0f - (float)i, v, B);
            C += v;
        }
        sbc[d] = B;
        sbc[D_MODEL + d] = C;
    }
    __syncthreads();

    const int lane = tid & 63;
    const int c    = lane & 31;        // float4 column (0..31) -> dims 4c..4c+3
    const int half = lane >> 5;        // 0 or 1

    const f32x4 b  = reinterpret_cast<const f32x4*>(sbc)[c];
    const f32x4 cv = reinterpret_cast<const f32x4*>(sbc + D_MODEL)[c];

    // Wave layout per iteration: lanes 0-31 -> rows R0..R0+3 (lane = float4
    // column c), lanes 32-63 -> rows R0+4..R0+7. One f32x4 t-load per thread
    // (broadcast within half-wave), 16 FMAs, 4 float4 NT stores (each store
    // instruction = two contiguous 512 B segments).
    const int waveGlobal = blockIdx.x * 4 + (tid >> 6);
    const int nWaves     = gridDim.x * 4;
    const int rowStride  = nWaves * 8;
    f32x4* __restrict__ outq = reinterpret_cast<f32x4*>(out);

    for (int R0 = waveGlobal * 8; R0 < n; R0 += rowStride) {
        const int R = R0 + half * 4;   // this thread's 4 rows: R..R+3
        if (R + 3 < n) {
            f32x4 t4 = *reinterpret_cast<const f32x4*>(t + R);
            float tv[4];
#pragma unroll
            for (int k = 0; k < 4; ++k) tv[k] = fminf(fmaxf(t4[k], 0.0f), 1.0f);
#pragma unroll
            for (int k = 0; k < 4; ++k) {
                f32x4 o;
                o.x = fmaf(tv[k], cv.x, b.x);
                o.y = fmaf(tv[k], cv.y, b.y);
                o.z = fmaf(tv[k], cv.z, b.z);
                o.w = fmaf(tv[k], cv.w, b.w);
                __builtin_nontemporal_store(o, &outq[(R + k) * 32 + c]);
            }
        } else {
            for (int k = 0; k < 4; ++k) {
                const int r = R + k;
                if (r < n) {
                    float tv = fminf(fmaxf(t[r], 0.0f), 1.0f);
                    f32x4 o;
                    o.x = fmaf(tv, cv.x, b.x);
                    o.y = fmaf(tv, cv.y, b.y);
                    o.z = fmaf(tv, cv.z, b.z);
                    o.w = fmaf(tv, cv.w, b.w);
                    __builtin_nontemporal_store(o, &outq[r * 32 + c]);
                }
            }
        }
    }
}

extern "C" void kernel_launch(void* const* d_in, const int* in_sizes, int n_in,
                              void* d_out, int out_size, void* d_ws, size_t ws_size,
                              hipStream_t stream) {
    const float* t  = (const float*)d_in[0];
    const float* cp = (const float*)d_in[1];
    float* out = (float*)d_out;
    const int n = in_sizes[0];

    // 2048 blocks x 256 threads = 8 blocks/CU -> full 32-wave occupancy.
    const int waveTasks  = (n + 7) / 8;          // 8 rows per wave-iter
    const int wantBlocks = (waveTasks + 3) / 4;  // 4 waves per block
    const int blocks = wantBlocks < 2048 ? wantBlocks : 2048;
    spline_fused<<<blocks, 256, 0, stream>>>(t, cp, out, n);
}

// Round 7
// 102.074 us; speedup vs baseline: 1.1684x; 1.0142x over previous
//
#include <hip/hip_runtime.h>

#define NUM_CP 64
#define D_MODEL 128

typedef float f32x4 __attribute__((ext_vector_type(4)));

// Exact algebraic collapse of the reference for t in [0,1]:
//   out[n][d] = B[d] + clip(t[n],0,1) * C[d]
//   B[d] = sum_{i=0}^{62} (1 - i) * cp[i][d]
//   C[d] = -cp[0][d] + sum_{i=1}^{62} cp[i][d]
//
// Single fused kernel. Coefficients reduced once per block (f32 -> LDS).
// Streaming loop: NT stores (R3/R5 A/B: +12 us over plain) and a software-
// pipelined t-load: the NEXT iteration's t4 is issued BEFORE this
// iteration's 4 stores, so the wait on the load result is vmcnt(5)-class
// (stores stay in flight) instead of vmcnt(0) (drain 4 HBM stores per
// iteration on the wave's critical path).
__global__ __launch_bounds__(256) void spline_fused(const float* __restrict__ t,
                                                    const float* __restrict__ cp,
                                                    float* __restrict__ out, int n) {
    __shared__ float sbc[2 * D_MODEL];

    const int tid = threadIdx.x;
    if (tid < D_MODEL) {
        const int d = tid;
        float v0 = cp[d];              // cp[0][d]
        float B = v0, C = -v0;
        for (int i = 1; i < NUM_CP - 1; ++i) {
            float v = cp[i * D_MODEL + d];
            B = fmaf(1.0f - (float)i, v, B);
            C += v;
        }
        sbc[d] = B;
        sbc[D_MODEL + d] = C;
    }
    __syncthreads();

    const int lane = tid & 63;
    const int c    = lane & 31;        // float4 column (0..31) -> dims 4c..4c+3
    const int half = lane >> 5;        // 0 or 1

    const f32x4 b  = reinterpret_cast<const f32x4*>(sbc)[c];
    const f32x4 cv = reinterpret_cast<const f32x4*>(sbc + D_MODEL)[c];

    // Wave layout per iteration: lanes 0-31 -> rows R0..R0+3 (lane = float4
    // column c), lanes 32-63 -> rows R0+4..R0+7.
    const int waveGlobal = blockIdx.x * 4 + (tid >> 6);
    const int nWaves     = gridDim.x * 4;
    const int rowStride  = nWaves * 8;
    f32x4* __restrict__ outq = reinterpret_cast<f32x4*>(out);

    int R0 = waveGlobal * 8;
    if (R0 >= n) return;

    bool full = (R0 + 7 < n);          // wave-uniform (n % 8 == 0 -> always)
    f32x4 t4;
    if (full) t4 = *reinterpret_cast<const f32x4*>(t + R0 + half * 4);

    for (; R0 < n; R0 += rowStride) {
        const int R0n = R0 + rowStride;
        const bool fulln = (R0n + 7 < n);
        f32x4 t4n;
        if (fulln) t4n = *reinterpret_cast<const f32x4*>(t + R0n + half * 4);

        const int R = R0 + half * 4;   // this thread's 4 rows: R..R+3
        if (full) {
            float tv[4];
#pragma unroll
            for (int k = 0; k < 4; ++k) tv[k] = fminf(fmaxf(t4[k], 0.0f), 1.0f);
#pragma unroll
            for (int k = 0; k < 4; ++k) {
                f32x4 o;
                o.x = fmaf(tv[k], cv.x, b.x);
                o.y = fmaf(tv[k], cv.y, b.y);
                o.z = fmaf(tv[k], cv.z, b.z);
                o.w = fmaf(tv[k], cv.w, b.w);
                __builtin_nontemporal_store(o, &outq[(R + k) * 32 + c]);
            }
        } else {
            for (int k = 0; k < 4; ++k) {
                const int r = R + k;
                if (r < n) {
                    float tv = fminf(fmaxf(t[r], 0.0f), 1.0f);
                    f32x4 o;
                    o.x = fmaf(tv, cv.x, b.x);
                    o.y = fmaf(tv, cv.y, b.y);
                    o.z = fmaf(tv, cv.z, b.z);
                    o.w = fmaf(tv, cv.w, b.w);
                    __builtin_nontemporal_store(o, &outq[r * 32 + c]);
                }
            }
        }
        t4 = t4n;
        full = fulln;
    }
}

extern "C" void kernel_launch(void* const* d_in, const int* in_sizes, int n_in,
                              void* d_out, int out_size, void* d_ws, size_t ws_size,
                              hipStream_t stream) {
    const float* t  = (const float*)d_in[0];
    const float* cp = (const float*)d_in[1];
    float* out = (float*)d_out;
    const int n = in_sizes[0];

    // 2048 blocks x 256 threads = 8 blocks/CU -> full 32-wave occupancy.
    const int waveTasks  = (n + 7) / 8;          // 8 rows per wave-iter
    const int wantBlocks = (waveTasks + 3) / 4;  // 4 waves per block
    const int blocks = wantBlocks < 2048 ? wantBlocks : 2048;
    spline_fused<<<blocks, 256, 0, stream>>>(t, cp, out, n);
}